// Round 1
// baseline (197.121 us; speedup 1.0000x reference)
//
#include <hip/hip_runtime.h>

// Problem constants (from reference setup_inputs)
#define N_PRE_C   50000
#define N_TYPES_C 20
#define N_BASIS_C 5
#define NB        2                    // batches
#define WORDS     784                  // ceil(50000/64)=782, padded to 784
#define SCAT_BLOCKS 2048               // persistent grid: 8 blocks/CU x 256 CUs

typedef unsigned long long ull;

// ---------------------------------------------------------------------------
// Kernel 1: pack rec_z_buf (B x N_PRE floats, binary) into a bitmask.
// Layout: mask[word][b] interleaved so one 16B LDS read covers both batches.
// Also zeroes out_t (grid-stride float4) so the separate memset dispatch goes
// away (zbuf == nullptr in the fallback path).
// ---------------------------------------------------------------------------
__global__ __launch_bounds__(256) void pack_spikes(const float* __restrict__ rec_z,
                                                   ull* __restrict__ mask,
                                                   float4* __restrict__ zbuf,
                                                   int zquads) {
    const int b = blockIdx.y;
    const int i = blockIdx.x * 256 + threadIdx.x;   // [0, WORDS*64)
    float v = 0.f;
    if (i < N_PRE_C) v = rec_z[b * N_PRE_C + i];
    const ull m = __ballot(v > 0.f);
    if ((threadIdx.x & 63) == 0) mask[(i >> 6) * NB + b] = m;

    if (zbuf != nullptr) {
        const int nt = gridDim.x * gridDim.y * 256;
        int q = (blockIdx.y * gridDim.x + blockIdx.x) * 256 + threadIdx.x;
        const float4 z = make_float4(0.f, 0.f, 0.f, 0.f);
        for (; q < zquads; q += nt) zbuf[q] = z;
    }
}

// ---------------------------------------------------------------------------
// Kernel 2: persistent scatter into per-(b,post,TYPE) accumulator.
// Grid-stride over quads of 4 synapses with a register prefetch double-buffer:
// the next iteration's 4x16B global loads are issued before the current quad
// is processed, so the wave always has independent VMEM in flight and the
// ds_read addresses (from last iteration's prefetch) are ready immediately.
// Mask staged in LDS ONCE per block (2048 blocks vs 9766 one-shot before).
// unsafeAtomicAdd = HW global_atomic_add_f32, fire-and-forget.
// ---------------------------------------------------------------------------
__device__ __forceinline__ void proc_m(int post, float wv, int tt, ull bit,
                                       ulonglong2 mw,
                                       float* __restrict__ out_t, int n_post) {
    if (((mw.x | mw.y) & bit) == 0ull) return;      // ~96% early-out
    const int o = post * N_TYPES_C + tt;            // 32-bit math: rows*20 < 2^31
    if (mw.x & bit) unsafeAtomicAdd(out_t + o, wv);
    if (mw.y & bit) unsafeAtomicAdd(out_t + n_post * N_TYPES_C + o, wv);
}

__global__ __launch_bounds__(256) void syn_scatter_t(
    const int4*  __restrict__ idx2,    // 2 synapses per int4 (post,pre,post,pre)
    const float4* __restrict__ w4,
    const int4*  __restrict__ sid4,
    const ull*   __restrict__ mask,
    float* __restrict__ out_t,         // [NB*n_post][N_TYPES] accumulator (zeroed)
    int n_post, int n_syn) {
    __shared__ __align__(16) ull sm[WORDS][2];
    {   // stage mask once per block with 16B loads
        const ulonglong2* msrc = (const ulonglong2*)mask;
        ulonglong2* mdst = (ulonglong2*)sm;
        for (int t = threadIdx.x; t < WORDS; t += 256) mdst[t] = msrc[t];
    }
    __syncthreads();
    const ulonglong2* sm2 = (const ulonglong2*)sm;

    const int nq = n_syn >> 2;                       // whole quads
    const int stride = gridDim.x * 256;
    int t = blockIdx.x * 256 + threadIdx.x;

    if (t < nq) {
        // prefetch iteration 0
        int4 p01 = idx2[(long)t * 2];
        int4 p23 = idx2[(long)t * 2 + 1];
        float4 wv = w4[t];
        int4 sv   = sid4[t];
        for (;;) {
            const int tn = t + stride;
            const bool vn = (tn < nq);
            int4 q01, q23, qs; float4 qw;
            if (vn) {                                // issue next-iter loads NOW
                q01 = idx2[(long)tn * 2];
                q23 = idx2[(long)tn * 2 + 1];
                qw  = w4[tn];
                qs  = sid4[tn];
            }
            // 4 x ds_read_b128; addresses come from registers loaded last iter
            const ulonglong2 m0 = sm2[p01.y >> 6];
            const ulonglong2 m1 = sm2[p01.w >> 6];
            const ulonglong2 m2 = sm2[p23.y >> 6];
            const ulonglong2 m3 = sm2[p23.w >> 6];
            proc_m(p01.x, wv.x, sv.x, 1ull << (p01.y & 63), m0, out_t, n_post);
            proc_m(p01.z, wv.y, sv.y, 1ull << (p01.w & 63), m1, out_t, n_post);
            proc_m(p23.x, wv.z, sv.z, 1ull << (p23.y & 63), m2, out_t, n_post);
            proc_m(p23.z, wv.w, sv.w, 1ull << (p23.w & 63), m3, out_t, n_post);
            if (!vn) break;
            t = tn; p01 = q01; p23 = q23; wv = qw; sv = qs;
        }
    }

    // scalar tail: n_syn % 4 leftover synapses handled by block 0
    const int rem = n_syn & 3;
    if (blockIdx.x == 0 && threadIdx.x < rem) {
        const int s = (n_syn & ~3) + threadIdx.x;
        const int*   idx = (const int*)idx2;
        const float* w   = (const float*)w4;
        const int*   sid = (const int*)sid4;
        const int post = idx[2 * s], pre = idx[2 * s + 1];
        proc_m(post, w[s], sid[s], 1ull << (pre & 63), sm2[pre >> 6],
               out_t, n_post);
    }
}

// ---------------------------------------------------------------------------
// Kernel 3: combine out_t [rows][20] x basis [20][5] -> out [rows][5].
// ---------------------------------------------------------------------------
__global__ __launch_bounds__(256) void combine_basis(
    const float* __restrict__ out_t,
    const float* __restrict__ basis,   // [N_TYPES][N_BASIS]
    float* __restrict__ out, int rows) {
    __shared__ float sb[N_TYPES_C * N_BASIS_C];
    if (threadIdx.x < N_TYPES_C * N_BASIS_C) sb[threadIdx.x] = basis[threadIdx.x];
    __syncthreads();

    const int r = blockIdx.x * 256 + threadIdx.x;
    if (r >= rows) return;
    const float4* p = (const float4*)(out_t + (long)r * N_TYPES_C);
    float4 v0 = p[0], v1 = p[1], v2 = p[2], v3 = p[3], v4 = p[4];
    float vt[N_TYPES_C] = {v0.x, v0.y, v0.z, v0.w, v1.x, v1.y, v1.z, v1.w,
                           v2.x, v2.y, v2.z, v2.w, v3.x, v3.y, v3.z, v3.w,
                           v4.x, v4.y, v4.z, v4.w};
    float acc[N_BASIS_C] = {0.f, 0.f, 0.f, 0.f, 0.f};
    #pragma unroll
    for (int t = 0; t < N_TYPES_C; ++t) {
        #pragma unroll
        for (int k = 0; k < N_BASIS_C; ++k)
            acc[k] += vt[t] * sb[t * N_BASIS_C + k];   // sb read is a broadcast
    }
    float* o = out + (long)r * N_BASIS_C;
    #pragma unroll
    for (int k = 0; k < N_BASIS_C; ++k) o[k] = acc[k];
}

// ---------------------------------------------------------------------------
// Fallback (only if ws too small): direct 5-atomic scatter into out.
// ---------------------------------------------------------------------------
__device__ __forceinline__ void proc_direct(int post, int pre, float wv, int tt,
                                            const ull (*sm)[2],
                                            const float (*sb)[N_BASIS_C],
                                            float* __restrict__ out, int n_post) {
    const int word = pre >> 6;
    const ull m0 = sm[word][0], m1 = sm[word][1];
    const ull bit = 1ull << (pre & 63);
    if (((m0 | m1) & bit) == 0ull) return;
    const float* bs = sb[tt];
    float c[N_BASIS_C];
    #pragma unroll
    for (int k = 0; k < N_BASIS_C; ++k) c[k] = wv * bs[k];
    if (m0 & bit) {
        float* o = out + (long)post * N_BASIS_C;
        #pragma unroll
        for (int k = 0; k < N_BASIS_C; ++k) unsafeAtomicAdd(o + k, c[k]);
    }
    if (m1 & bit) {
        float* o = out + (long)(n_post + post) * N_BASIS_C;
        #pragma unroll
        for (int k = 0; k < N_BASIS_C; ++k) unsafeAtomicAdd(o + k, c[k]);
    }
}

__global__ __launch_bounds__(256) void syn_scatter_direct(
    const int4* __restrict__ idx2, const float4* __restrict__ w4,
    const int4* __restrict__ sid4, const float* __restrict__ basis,
    const ull* __restrict__ mask, float* __restrict__ out,
    int n_post, int n_syn) {
    __shared__ __align__(16) ull sm[WORDS][2];
    __shared__ float sb[N_TYPES_C][N_BASIS_C];
    for (int t = threadIdx.x; t < WORDS * 2; t += 256) ((ull*)sm)[t] = mask[t];
    for (int t = threadIdx.x; t < N_TYPES_C * N_BASIS_C; t += 256)
        ((float*)sb)[t] = basis[t];
    __syncthreads();
    const int t = blockIdx.x * 256 + threadIdx.x;
    const long base = (long)t * 4;
    if (base >= n_syn) return;
    if (base + 4 <= n_syn) {
        const int4   p01 = idx2[(long)t * 2];
        const int4   p23 = idx2[(long)t * 2 + 1];
        const float4 wv  = w4[t];
        const int4   sv  = sid4[t];
        proc_direct(p01.x, p01.y, wv.x, sv.x, sm, sb, out, n_post);
        proc_direct(p01.z, p01.w, wv.y, sv.y, sm, sb, out, n_post);
        proc_direct(p23.x, p23.y, wv.z, sv.z, sm, sb, out, n_post);
        proc_direct(p23.z, p23.w, wv.w, sv.w, sm, sb, out, n_post);
    } else {
        const int*   idx = (const int*)idx2;
        const float* w   = (const float*)w4;
        const int*   sid = (const int*)sid4;
        for (long s = base; s < n_syn; ++s)
            proc_direct(idx[2 * s], idx[2 * s + 1], w[s], sid[s], sm, sb, out, n_post);
    }
}

extern "C" void kernel_launch(void* const* d_in, const int* in_sizes, int n_in,
                              void* d_out, int out_size, void* d_ws, size_t ws_size,
                              hipStream_t stream) {
    const float* rec_z   = (const float*)d_in[0];
    const float* weights = (const float*)d_in[1];
    const float* basis   = (const float*)d_in[2];
    const int*   synidx  = (const int*)d_in[3];
    const int*   synids  = (const int*)d_in[4];
    float*       out     = (float*)d_out;

    const int n_syn  = in_sizes[4];
    const int rows   = out_size / N_BASIS_C;       // NB * n_post
    const int n_post = rows / NB;

    // Workspace layout: out_t [rows][N_TYPES] floats, then mask.
    const size_t out_t_bytes = (size_t)rows * N_TYPES_C * sizeof(float);
    const size_t mask_bytes  = (size_t)WORDS * NB * sizeof(ull);

    if (ws_size >= out_t_bytes + mask_bytes) {
        float* out_t = (float*)d_ws;
        ull*   mask  = (ull*)((char*)d_ws + out_t_bytes);

        // rows*N_TYPES_C*4 bytes is always a multiple of 16 (20 floats = 80B/row)
        const int zquads = (int)(out_t_bytes / sizeof(float4));

        pack_spikes<<<dim3(WORDS * 64 / 256, NB), 256, 0, stream>>>(
            rec_z, mask, (float4*)out_t, zquads);

        int blocks = SCAT_BLOCKS;
        const int nq   = n_syn >> 2;
        const int maxb = (nq + 255) / 256;
        if (blocks > maxb) blocks = maxb;
        if (blocks < 1)    blocks = 1;
        syn_scatter_t<<<blocks, 256, 0, stream>>>(
            (const int4*)synidx, (const float4*)weights, (const int4*)synids,
            mask, out_t, n_post, n_syn);

        combine_basis<<<(rows + 255) / 256, 256, 0, stream>>>(out_t, basis, out, rows);
    } else {
        // Fallback: direct 5-atomic scatter.
        ull* mask = (ull*)d_ws;
        hipMemsetAsync(d_out, 0, (size_t)out_size * sizeof(float), stream);
        pack_spikes<<<dim3(WORDS * 64 / 256, NB), 256, 0, stream>>>(
            rec_z, mask, nullptr, 0);
        const int blocks = ((n_syn + 3) / 4 + 255) / 256;
        syn_scatter_direct<<<blocks, 256, 0, stream>>>(
            (const int4*)synidx, (const float4*)weights, (const int4*)synids,
            basis, mask, out, n_post, n_syn);
    }
}